// Round 2
// baseline (941.364 us; speedup 1.0000x reference)
//
#include <hip/hip_runtime.h>

#define N_NODES 65536
#define N_EDGES 1048576
#define E_TOTAL (N_EDGES + N_NODES)
#define VOCAB 50000
#define HIDDEN 256
#define NUM_GRAPHS 64
#define NEG_SLOPE 0.2f
#define SM_EPS 1e-16f

typedef _Float16 f16x8 __attribute__((ext_vector_type(8)));
typedef _Float16 f16x4 __attribute__((ext_vector_type(4)));
typedef float f32x4 __attribute__((ext_vector_type(4)));

// ---------------- gather: x = (fp16) emb[nodes] ----------------
__global__ __launch_bounds__(256) void gather_kernel(const int* __restrict__ nodes,
    const float* __restrict__ emb, _Float16* __restrict__ x) {
    int i = blockIdx.x;
    int t = threadIdx.x;
    x[(size_t)i * HIDDEN + t] = (_Float16)emb[(size_t)nodes[i] * HIDDEN + t];
}

// ---------------- weight transpose+convert: WT[mat][n][k] = (fp16) W[mat][k][n] ----------------
__global__ __launch_bounds__(256) void convert_wt_kernel(const float* __restrict__ Wg,
    const float* __restrict__ Wl, _Float16* __restrict__ WT) {
    int mat = blockIdx.y;
    int n = blockIdx.x;
    int k = threadIdx.x;
    const float* W = (mat < 3) ? (Wg + (size_t)mat * HIDDEN * HIDDEN)
                               : (Wl + (size_t)(mat - 3) * HIDDEN * HIDDEN);
    WT[(size_t)mat * HIDDEN * HIDDEN + (size_t)n * HIDDEN + k] = (_Float16)W[(size_t)k * HIDDEN + n];
}

// ---------------- CSR build (by dst) ----------------
__global__ __launch_bounds__(256) void hist_kernel(const int* __restrict__ ei, int* __restrict__ counts) {
    int e = blockIdx.x * 256 + threadIdx.x;
    if (e >= E_TOTAL) return;
    int dst = (e < N_EDGES) ? ei[N_EDGES + e] : (e - N_EDGES);
    atomicAdd(&counts[dst], 1);
}

__global__ __launch_bounds__(1024) void scan_kernel(const int* __restrict__ counts,
    int* __restrict__ row_ptr, int* __restrict__ cursor) {
    __shared__ int sp[1024];
    int t = threadIdx.x;
    int base = t * 64;
    int s = 0;
    for (int i = 0; i < 64; i++) s += counts[base + i];
    sp[t] = s;
    __syncthreads();
    for (int d = 1; d < 1024; d <<= 1) {
        int v = (t >= d) ? sp[t - d] : 0;
        __syncthreads();
        sp[t] += v;
        __syncthreads();
    }
    int run = sp[t] - s;
    for (int i = 0; i < 64; i++) {
        int c = counts[base + i];
        row_ptr[base + i] = run;
        cursor[base + i] = run;
        run += c;
    }
    if (t == 1023) row_ptr[N_NODES] = run;
}

__global__ __launch_bounds__(256) void scatter_kernel(const int* __restrict__ ei,
    int* __restrict__ cursor, int* __restrict__ src_sorted) {
    int e = blockIdx.x * 256 + threadIdx.x;
    if (e >= E_TOTAL) return;
    int src, dst;
    if (e < N_EDGES) { src = ei[e]; dst = ei[N_EDGES + e]; }
    else             { src = dst = e - N_EDGES; }
    int pos = atomicAdd(&cursor[dst], 1);
    src_sorted[pos] = src;
}

// ---------------- fp16 MFMA GEMM: BM=128, BN=128, BK=32, 1024 blocks (4/CU) ----
// C[M,256] = A[M,256] @ W (WT[n][k]). Grid (M/128, 2); blockIdx.y picks the
// 128-col half. FUSED: partial row-dots vs a_s/a_d atomicAdd'ed into es/ed
// (caller zeroes es/ed first). Template tag -> distinct mangled names in prof.
#define PAD_K 40
template <bool FUSED>
__global__ __launch_bounds__(256) void gemm_f16_kernel(const _Float16* __restrict__ A,
    const _Float16* __restrict__ WT, const float* __restrict__ bias,
    _Float16* __restrict__ C,
    const float* __restrict__ a_s, const float* __restrict__ a_d,
    float* __restrict__ es, float* __restrict__ ed) {
    __shared__ _Float16 As[128][PAD_K];   // 10240 B
    __shared__ _Float16 Bs[128][PAD_K];   // 10240 B
    int tid = threadIdx.x;
    int wave = tid >> 6;
    int lane = tid & 63;
    int quad = lane >> 4;
    int l16 = lane & 15;
    int m0 = blockIdx.x * 128;
    int n0 = blockIdx.y * 128;

    f32x4 acc[2][8];
    #pragma unroll
    for (int rt = 0; rt < 2; rt++)
        #pragma unroll
        for (int ct = 0; ct < 8; ct++)
            acc[rt][ct] = (f32x4){0.f, 0.f, 0.f, 0.f};

    for (int k0 = 0; k0 < HIDDEN; k0 += 32) {
        __syncthreads();
        // stage A: 128 rows x 32 halfs = 512 16B-chunks; 2 per thread
        #pragma unroll
        for (int i = 0; i < 2; i++) {
            int c = tid + i * 256;
            int row = c >> 2, q = c & 3;
            *(f16x8*)&As[row][q * 8] =
                *(const f16x8*)(A + (size_t)(m0 + row) * HIDDEN + k0 + q * 8);
        }
        // stage B: 128 rows (cols n0..n0+127) x 32 halfs; 2 per thread
        #pragma unroll
        for (int i = 0; i < 2; i++) {
            int c = tid + i * 256;
            int row = c >> 2, q = c & 3;
            *(f16x8*)&Bs[row][q * 8] =
                *(const f16x8*)(WT + (size_t)(n0 + row) * HIDDEN + k0 + q * 8);
        }
        __syncthreads();
        f16x8 a0 = *(const f16x8*)&As[wave * 32 + l16][quad * 8];
        f16x8 a1 = *(const f16x8*)&As[wave * 32 + 16 + l16][quad * 8];
        #pragma unroll
        for (int ct = 0; ct < 8; ct++) {
            f16x8 b = *(const f16x8*)&Bs[ct * 16 + l16][quad * 8];
            acc[0][ct] = __builtin_amdgcn_mfma_f32_16x16x32_f16(a0, b, acc[0][ct], 0, 0, 0);
            acc[1][ct] = __builtin_amdgcn_mfma_f32_16x16x32_f16(a1, b, acc[1][ct], 0, 0, 0);
        }
    }
    // epilogue: C/D layout col=lane&15, row=quad*4+reg
    #pragma unroll
    for (int rt = 0; rt < 2; rt++) {
        #pragma unroll
        for (int ct = 0; ct < 8; ct++) {
            int col = n0 + ct * 16 + l16;
            float bv = (bias != nullptr) ? bias[col] : 0.f;
            int rowbase = m0 + wave * 32 + rt * 16 + quad * 4;
            #pragma unroll
            for (int r = 0; r < 4; r++) {
                C[(size_t)(rowbase + r) * HIDDEN + col] = (_Float16)(acc[rt][ct][r] + bv);
            }
        }
    }
    // fused dots: partial over this block's 128 cols, atomicAdd into es/ed
    if (FUSED) {
        #pragma unroll
        for (int rt = 0; rt < 2; rt++) {
            float ds0 = 0.f, ds1 = 0.f, ds2 = 0.f, ds3 = 0.f;
            float dd0 = 0.f, dd1 = 0.f, dd2 = 0.f, dd3 = 0.f;
            #pragma unroll
            for (int ct = 0; ct < 8; ct++) {
                int col = n0 + ct * 16 + l16;
                float av = a_s[col];
                float dv = a_d[col];
                ds0 += acc[rt][ct][0] * av; dd0 += acc[rt][ct][0] * dv;
                ds1 += acc[rt][ct][1] * av; dd1 += acc[rt][ct][1] * dv;
                ds2 += acc[rt][ct][2] * av; dd2 += acc[rt][ct][2] * dv;
                ds3 += acc[rt][ct][3] * av; dd3 += acc[rt][ct][3] * dv;
            }
            #pragma unroll
            for (int off = 1; off < 16; off <<= 1) {
                ds0 += __shfl_xor(ds0, off); dd0 += __shfl_xor(dd0, off);
                ds1 += __shfl_xor(ds1, off); dd1 += __shfl_xor(dd1, off);
                ds2 += __shfl_xor(ds2, off); dd2 += __shfl_xor(dd2, off);
                ds3 += __shfl_xor(ds3, off); dd3 += __shfl_xor(dd3, off);
            }
            if (l16 == 0) {
                int rowbase = m0 + wave * 32 + rt * 16 + quad * 4;
                atomicAdd(&es[rowbase + 0], ds0); atomicAdd(&ed[rowbase + 0], dd0);
                atomicAdd(&es[rowbase + 1], ds1); atomicAdd(&ed[rowbase + 1], dd1);
                atomicAdd(&es[rowbase + 2], ds2); atomicAdd(&ed[rowbase + 2], dd2);
                atomicAdd(&es[rowbase + 3], ds3); atomicAdd(&ed[rowbase + 3], dd3);
            }
        }
    }
}

// ---------------- wave-per-dst SINGLE-PASS online-softmax aggregate (fp16 h) ----
// All 64 lanes of a wave see the identical edge stream for their dst, so the
// running (m, denom) is tracked redundantly per-lane: ZERO shuffles, ZERO wbuf
// traffic, one edge-list traversal instead of three. On a max update the
// 4-float per-lane accumulator is rescaled by exp(m_old - m_new) (flash-attn
// style). Final m equals the exact segment max -> same math as reference.
__global__ __launch_bounds__(256) void agg_kernel(const _Float16* __restrict__ h,
    const int* __restrict__ row_ptr, const int* __restrict__ src_sorted,
    const float* __restrict__ es, const float* __restrict__ ed,
    const float* __restrict__ bg, _Float16* __restrict__ g) {
    int gtid = blockIdx.x * 256 + threadIdx.x;
    int dst = gtid >> 6;
    int lane = threadIdx.x & 63;
    if (dst >= N_NODES) return;
    int start = row_ptr[dst];
    int end = row_ptr[dst + 1];
    float edd = ed[dst];
    const _Float16* hl = h + (size_t)lane * 4;   // this lane's 4-dim column slice

    float m = -1e30f;
    float denom = 0.f;
    float4 acc = make_float4(0.f, 0.f, 0.f, 0.f);

    int i = start;
    for (; i + 3 < end; i += 4) {
        int s0 = src_sorted[i + 0];
        int s1 = src_sorted[i + 1];
        int s2 = src_sorted[i + 2];
        int s3 = src_sorted[i + 3];
        // issue the 4 row loads + 4 es gathers up front (independent, overlap)
        f16x4 r0 = *(const f16x4*)(hl + (size_t)s0 * HIDDEN);
        f16x4 r1 = *(const f16x4*)(hl + (size_t)s1 * HIDDEN);
        f16x4 r2 = *(const f16x4*)(hl + (size_t)s2 * HIDDEN);
        f16x4 r3 = *(const f16x4*)(hl + (size_t)s3 * HIDDEN);
        float e0 = es[s0] + edd; e0 = (e0 > 0.f) ? e0 : NEG_SLOPE * e0;
        float e1 = es[s1] + edd; e1 = (e1 > 0.f) ? e1 : NEG_SLOPE * e1;
        float e2 = es[s2] + edd; e2 = (e2 > 0.f) ? e2 : NEG_SLOPE * e2;
        float e3 = es[s3] + edd; e3 = (e3 > 0.f) ? e3 : NEG_SLOPE * e3;
        float me = fmaxf(fmaxf(e0, e1), fmaxf(e2, e3));
        if (me > m) {                       // wave-uniform branch, rare
            float sc = __expf(m - me);      // exp(-inf)=0 on first hit: safe
            denom *= sc;
            acc.x *= sc; acc.y *= sc; acc.z *= sc; acc.w *= sc;
            m = me;
        }
        float w0 = __expf(e0 - m);
        float w1 = __expf(e1 - m);
        float w2 = __expf(e2 - m);
        float w3 = __expf(e3 - m);
        denom += (w0 + w1) + (w2 + w3);
        acc.x += w0 * (float)r0[0] + w1 * (float)r1[0] + w2 * (float)r2[0] + w3 * (float)r3[0];
        acc.y += w0 * (float)r0[1] + w1 * (float)r1[1] + w2 * (float)r2[1] + w3 * (float)r3[1];
        acc.z += w0 * (float)r0[2] + w1 * (float)r1[2] + w2 * (float)r2[2] + w3 * (float)r3[2];
        acc.w += w0 * (float)r0[3] + w1 * (float)r1[3] + w2 * (float)r2[3] + w3 * (float)r3[3];
    }
    for (; i < end; i++) {
        int s0 = src_sorted[i];
        f16x4 r0 = *(const f16x4*)(hl + (size_t)s0 * HIDDEN);
        float e0 = es[s0] + edd; e0 = (e0 > 0.f) ? e0 : NEG_SLOPE * e0;
        if (e0 > m) {
            float sc = __expf(m - e0);
            denom *= sc;
            acc.x *= sc; acc.y *= sc; acc.z *= sc; acc.w *= sc;
            m = e0;
        }
        float w0 = __expf(e0 - m);
        denom += w0;
        acc.x += w0 * (float)r0[0];
        acc.y += w0 * (float)r0[1];
        acc.z += w0 * (float)r0[2];
        acc.w += w0 * (float)r0[3];
    }

    float inv = 1.0f / (denom + SM_EPS);
    float4 b4 = *(const float4*)(bg + lane * 4);
    f16x4 outv;
    outv[0] = (_Float16)fmaxf(acc.x * inv + b4.x, 0.f);
    outv[1] = (_Float16)fmaxf(acc.y * inv + b4.y, 0.f);
    outv[2] = (_Float16)fmaxf(acc.z * inv + b4.z, 0.f);
    outv[3] = (_Float16)fmaxf(acc.w * inv + b4.w, 0.f);
    *(f16x4*)(g + (size_t)dst * HIDDEN + lane * 4) = outv;
}

// ---------------- graph boundaries: batch is SORTED -> binary search ----------------
__global__ __launch_bounds__(128) void graph_bounds_kernel(const int* __restrict__ batch,
    int* __restrict__ gstart) {
    int g = threadIdx.x;
    if (g > NUM_GRAPHS) return;
    if (g == NUM_GRAPHS) { gstart[NUM_GRAPHS] = N_NODES; return; }
    int lo = 0, hi = N_NODES;
    while (lo < hi) {
        int mid = (lo + hi) >> 1;
        if (batch[mid] < g) lo = mid + 1; else hi = mid;
    }
    gstart[g] = lo;
}

// ---------------- mean pool: owner-computes partial reduction (fp16 x) ----------------
#define POOL_SPLITS 16
__global__ __launch_bounds__(256) void pool_partial_kernel(const _Float16* __restrict__ x,
    const int* __restrict__ gstart, float* __restrict__ pooledT) {
    int g = blockIdx.x;
    int chunk = blockIdx.y;
    int t = threadIdx.x;
    int s = gstart[g];
    int e = gstart[g + 1];
    int n = e - s;
    int per = (n + POOL_SPLITS - 1) / POOL_SPLITS;
    int r0 = s + chunk * per;
    int r1 = min(r0 + per, e);
    if (r0 >= r1) return;
    float acc = 0.f;
    for (int r = r0; r < r1; r++) acc += (float)x[(size_t)r * HIDDEN + t];
    atomicAdd(&pooledT[t * NUM_GRAPHS + g], acc);
}

__global__ __launch_bounds__(256) void mean_kernel(const float* __restrict__ pooledT,
    const int* __restrict__ gstart, float* __restrict__ meanT) {
    int i = blockIdx.x * 256 + threadIdx.x;
    int g = i & (NUM_GRAPHS - 1);
    float c = (float)max(gstart[g + 1] - gstart[g], 1);
    meanT[i] = pooledT[i] / c;
}

// ---------------- final: out[64,50000] = pooled @ Wout + bout (fp32) ----------------
// Intra-block g-split: 256 threads = 64 j-columns x 4 g-chunks of 16.
// Each thread keeps 16 accumulators (~24 VGPR, no spill). All 4 waves load
// the SAME 64 Wout floats per k (wave 0 misses, waves 1-3 hit L1/L2), so
// Wout streams from HBM exactly once (51 MB). meanT index is wave-uniform
// -> scalarized s_load_dwordx16. 782 blocks x 4 waves = good TLP.
__global__ __launch_bounds__(256) void final_kernel(const float* __restrict__ meanT,
    const float* __restrict__ Wout, const float* __restrict__ bout, float* __restrict__ out) {
    int j = blockIdx.x * 64 + (threadIdx.x & 63);
    int g0 = (threadIdx.x >> 6) * 16;     // wave-uniform
    if (j >= VOCAB) return;
    float acc[16];
    #pragma unroll
    for (int g = 0; g < 16; g++) acc[g] = 0.f;
    #pragma unroll 4
    for (int k = 0; k < HIDDEN; k++) {
        float w = Wout[(size_t)k * VOCAB + j];
        const float* mrow = meanT + k * NUM_GRAPHS + g0;
        #pragma unroll
        for (int g = 0; g < 16; g++) acc[g] += mrow[g] * w;
    }
    float b = bout[j];
    #pragma unroll
    for (int g = 0; g < 16; g++) out[(size_t)(g0 + g) * VOCAB + j] = acc[g] + b;
}

extern "C" void kernel_launch(void* const* d_in, const int* in_sizes, int n_in,
                              void* d_out, int out_size, void* d_ws, size_t ws_size,
                              hipStream_t stream) {
    const int*   nodes = (const int*)d_in[0];
    const int*   ei    = (const int*)d_in[1];
    const int*   batch = (const int*)d_in[2];
    const float* emb   = (const float*)d_in[3];
    const float* Wg    = (const float*)d_in[4];
    const float* a_src = (const float*)d_in[5];
    const float* a_dst = (const float*)d_in[6];
    const float* bg    = (const float*)d_in[7];
    const float* Wl    = (const float*)d_in[8];
    const float* bl    = (const float*)d_in[9];
    const float* Wout  = (const float*)d_in[10];
    const float* bout  = (const float*)d_in[11];
    float* out = (float*)d_out;

    char* ws = (char*)d_ws;
    size_t off = 0;
    auto alloc = [&](size_t bytes) -> void* {
        void* p = ws + off;
        off += (bytes + 255) & ~(size_t)255;
        return p;
    };
    _Float16* bufA    = (_Float16*)alloc((size_t)N_NODES * HIDDEN * 2);
    _Float16* bufB    = (_Float16*)alloc((size_t)N_NODES * HIDDEN * 2);
    _Float16* WT      = (_Float16*)alloc((size_t)6 * HIDDEN * HIDDEN * 2);
    float* es         = (float*)alloc((size_t)N_NODES * 4);
    float* ed         = (float*)alloc((size_t)N_NODES * 4);
    int*   counts     = (int*)alloc((size_t)N_NODES * 4);
    int*   row_ptr    = (int*)alloc((size_t)(N_NODES + 1) * 4);
    int*   cursor     = (int*)alloc((size_t)N_NODES * 4);
    int*   src_sorted = (int*)alloc((size_t)E_TOTAL * 4);
    float* pooledT    = (float*)alloc((size_t)HIDDEN * NUM_GRAPHS * 4);
    float* meanT      = (float*)alloc((size_t)HIDDEN * NUM_GRAPHS * 4);
    int*   gstart     = (int*)alloc((size_t)(NUM_GRAPHS + 1) * 4);

    hipMemsetAsync(counts, 0, (size_t)N_NODES * 4, stream);
    hipMemsetAsync(pooledT, 0, (size_t)HIDDEN * NUM_GRAPHS * 4, stream);

    convert_wt_kernel<<<dim3(HIDDEN, 6), 256, 0, stream>>>(Wg, Wl, WT);
    gather_kernel<<<N_NODES, 256, 0, stream>>>(nodes, emb, bufA);
    hist_kernel<<<(E_TOTAL + 255) / 256, 256, 0, stream>>>(ei, counts);
    scan_kernel<<<1, 1024, 0, stream>>>(counts, row_ptr, cursor);
    scatter_kernel<<<(E_TOTAL + 255) / 256, 256, 0, stream>>>(ei, cursor, src_sorted);

    _Float16* cur = bufA;
    _Float16* oth = bufB;
    for (int l = 0; l < 3; l++) {
        // zero es/ed for the fused-partial atomics
        hipMemsetAsync(es, 0, (size_t)N_NODES * 4, stream);
        hipMemsetAsync(ed, 0, (size_t)N_NODES * 4, stream);
        gemm_f16_kernel<true><<<dim3(N_NODES / 128, 2), 256, 0, stream>>>(
            cur, WT + (size_t)l * HIDDEN * HIDDEN, nullptr, oth,
            a_src + (size_t)l * HIDDEN, a_dst + (size_t)l * HIDDEN, es, ed);
        agg_kernel<<<N_NODES / 4, 256, 0, stream>>>(
            oth, row_ptr, src_sorted, es, ed, bg + (size_t)l * HIDDEN, cur);
        gemm_f16_kernel<false><<<dim3(N_NODES / 128, 2), 256, 0, stream>>>(
            cur, WT + (size_t)(3 + l) * HIDDEN * HIDDEN, bl + (size_t)l * HIDDEN, oth,
            nullptr, nullptr, nullptr, nullptr);
        _Float16* t = cur; cur = oth; oth = t;
    }

    graph_bounds_kernel<<<1, 128, 0, stream>>>(batch, gstart);
    pool_partial_kernel<<<dim3(NUM_GRAPHS, POOL_SPLITS), 256, 0, stream>>>(cur, gstart, pooledT);
    mean_kernel<<<(HIDDEN * NUM_GRAPHS) / 256, 256, 0, stream>>>(pooledT, gstart, meanT);
    final_kernel<<<dim3((VOCAB + 63) / 64), 256, 0, stream>>>(meanT, Wout, bout, out);
}

// Round 3
// 835.480 us; speedup vs baseline: 1.1267x; 1.1267x over previous
//
#include <hip/hip_runtime.h>

#define N_NODES 65536
#define N_EDGES 1048576
#define E_TOTAL (N_EDGES + N_NODES)
#define VOCAB 50000
#define HIDDEN 256
#define NUM_GRAPHS 64
#define NEG_SLOPE 0.2f
#define SM_EPS 1e-16f

typedef _Float16 f16x8 __attribute__((ext_vector_type(8)));
typedef _Float16 f16x4 __attribute__((ext_vector_type(4)));
typedef float f32x4 __attribute__((ext_vector_type(4)));

// ---------------- gather: x = (fp16) emb[nodes] ----------------
__global__ __launch_bounds__(256) void gather_kernel(const int* __restrict__ nodes,
    const float* __restrict__ emb, _Float16* __restrict__ x) {
    int i = blockIdx.x;
    int t = threadIdx.x;
    x[(size_t)i * HIDDEN + t] = (_Float16)emb[(size_t)nodes[i] * HIDDEN + t];
}

// ---------------- weight transpose+convert: WT[mat][n][k] = (fp16) W[mat][k][n] ----------------
__global__ __launch_bounds__(256) void convert_wt_kernel(const float* __restrict__ Wg,
    const float* __restrict__ Wl, _Float16* __restrict__ WT) {
    int mat = blockIdx.y;
    int n = blockIdx.x;
    int k = threadIdx.x;
    const float* W = (mat < 3) ? (Wg + (size_t)mat * HIDDEN * HIDDEN)
                               : (Wl + (size_t)(mat - 3) * HIDDEN * HIDDEN);
    WT[(size_t)mat * HIDDEN * HIDDEN + (size_t)n * HIDDEN + k] = (_Float16)W[(size_t)k * HIDDEN + n];
}

// ---------------- CSR build (by dst) ----------------
__global__ __launch_bounds__(256) void hist_kernel(const int* __restrict__ ei, int* __restrict__ counts) {
    int e = blockIdx.x * 256 + threadIdx.x;
    if (e >= E_TOTAL) return;
    int dst = (e < N_EDGES) ? ei[N_EDGES + e] : (e - N_EDGES);
    atomicAdd(&counts[dst], 1);
}

__global__ __launch_bounds__(1024) void scan_kernel(const int* __restrict__ counts,
    int* __restrict__ row_ptr, int* __restrict__ cursor) {
    __shared__ int sp[1024];
    int t = threadIdx.x;
    int base = t * 64;
    int s = 0;
    for (int i = 0; i < 64; i++) s += counts[base + i];
    sp[t] = s;
    __syncthreads();
    for (int d = 1; d < 1024; d <<= 1) {
        int v = (t >= d) ? sp[t - d] : 0;
        __syncthreads();
        sp[t] += v;
        __syncthreads();
    }
    int run = sp[t] - s;
    for (int i = 0; i < 64; i++) {
        int c = counts[base + i];
        row_ptr[base + i] = run;
        cursor[base + i] = run;
        run += c;
    }
    if (t == 1023) row_ptr[N_NODES] = run;
}

__global__ __launch_bounds__(256) void scatter_kernel(const int* __restrict__ ei,
    int* __restrict__ cursor, int* __restrict__ src_sorted) {
    int e = blockIdx.x * 256 + threadIdx.x;
    if (e >= E_TOTAL) return;
    int src, dst;
    if (e < N_EDGES) { src = ei[e]; dst = ei[N_EDGES + e]; }
    else             { src = dst = e - N_EDGES; }
    int pos = atomicAdd(&cursor[dst], 1);
    src_sorted[pos] = src;
}

// ---------------- fp16 MFMA GEMM: BM=128, BN=128, BK=32, 1024 blocks (4/CU) ----
// C[M,256] = A[M,256] @ W (WT[n][k]). Grid (M/128, 2); blockIdx.y picks the
// 128-col half. FUSED: partial row-dots vs a_s/a_d atomicAdd'ed into es/ed
// (caller zeroes es/ed first). Template tag -> distinct mangled names in prof.
#define PAD_K 40
template <bool FUSED>
__global__ __launch_bounds__(256) void gemm_f16_kernel(const _Float16* __restrict__ A,
    const _Float16* __restrict__ WT, const float* __restrict__ bias,
    _Float16* __restrict__ C,
    const float* __restrict__ a_s, const float* __restrict__ a_d,
    float* __restrict__ es, float* __restrict__ ed) {
    __shared__ _Float16 As[128][PAD_K];   // 10240 B
    __shared__ _Float16 Bs[128][PAD_K];   // 10240 B
    int tid = threadIdx.x;
    int wave = tid >> 6;
    int lane = tid & 63;
    int quad = lane >> 4;
    int l16 = lane & 15;
    int m0 = blockIdx.x * 128;
    int n0 = blockIdx.y * 128;

    f32x4 acc[2][8];
    #pragma unroll
    for (int rt = 0; rt < 2; rt++)
        #pragma unroll
        for (int ct = 0; ct < 8; ct++)
            acc[rt][ct] = (f32x4){0.f, 0.f, 0.f, 0.f};

    for (int k0 = 0; k0 < HIDDEN; k0 += 32) {
        __syncthreads();
        // stage A: 128 rows x 32 halfs = 512 16B-chunks; 2 per thread
        #pragma unroll
        for (int i = 0; i < 2; i++) {
            int c = tid + i * 256;
            int row = c >> 2, q = c & 3;
            *(f16x8*)&As[row][q * 8] =
                *(const f16x8*)(A + (size_t)(m0 + row) * HIDDEN + k0 + q * 8);
        }
        // stage B: 128 rows (cols n0..n0+127) x 32 halfs; 2 per thread
        #pragma unroll
        for (int i = 0; i < 2; i++) {
            int c = tid + i * 256;
            int row = c >> 2, q = c & 3;
            *(f16x8*)&Bs[row][q * 8] =
                *(const f16x8*)(WT + (size_t)(n0 + row) * HIDDEN + k0 + q * 8);
        }
        __syncthreads();
        f16x8 a0 = *(const f16x8*)&As[wave * 32 + l16][quad * 8];
        f16x8 a1 = *(const f16x8*)&As[wave * 32 + 16 + l16][quad * 8];
        #pragma unroll
        for (int ct = 0; ct < 8; ct++) {
            f16x8 b = *(const f16x8*)&Bs[ct * 16 + l16][quad * 8];
            acc[0][ct] = __builtin_amdgcn_mfma_f32_16x16x32_f16(a0, b, acc[0][ct], 0, 0, 0);
            acc[1][ct] = __builtin_amdgcn_mfma_f32_16x16x32_f16(a1, b, acc[1][ct], 0, 0, 0);
        }
    }
    // epilogue: C/D layout col=lane&15, row=quad*4+reg
    #pragma unroll
    for (int rt = 0; rt < 2; rt++) {
        #pragma unroll
        for (int ct = 0; ct < 8; ct++) {
            int col = n0 + ct * 16 + l16;
            float bv = (bias != nullptr) ? bias[col] : 0.f;
            int rowbase = m0 + wave * 32 + rt * 16 + quad * 4;
            #pragma unroll
            for (int r = 0; r < 4; r++) {
                C[(size_t)(rowbase + r) * HIDDEN + col] = (_Float16)(acc[rt][ct][r] + bv);
            }
        }
    }
    // fused dots: partial over this block's 128 cols, atomicAdd into es/ed
    if (FUSED) {
        #pragma unroll
        for (int rt = 0; rt < 2; rt++) {
            float ds0 = 0.f, ds1 = 0.f, ds2 = 0.f, ds3 = 0.f;
            float dd0 = 0.f, dd1 = 0.f, dd2 = 0.f, dd3 = 0.f;
            #pragma unroll
            for (int ct = 0; ct < 8; ct++) {
                int col = n0 + ct * 16 + l16;
                float av = a_s[col];
                float dv = a_d[col];
                ds0 += acc[rt][ct][0] * av; dd0 += acc[rt][ct][0] * dv;
                ds1 += acc[rt][ct][1] * av; dd1 += acc[rt][ct][1] * dv;
                ds2 += acc[rt][ct][2] * av; dd2 += acc[rt][ct][2] * dv;
                ds3 += acc[rt][ct][3] * av; dd3 += acc[rt][ct][3] * dv;
            }
            #pragma unroll
            for (int off = 1; off < 16; off <<= 1) {
                ds0 += __shfl_xor(ds0, off); dd0 += __shfl_xor(dd0, off);
                ds1 += __shfl_xor(ds1, off); dd1 += __shfl_xor(dd1, off);
                ds2 += __shfl_xor(ds2, off); dd2 += __shfl_xor(dd2, off);
                ds3 += __shfl_xor(ds3, off); dd3 += __shfl_xor(dd3, off);
            }
            if (l16 == 0) {
                int rowbase = m0 + wave * 32 + rt * 16 + quad * 4;
                atomicAdd(&es[rowbase + 0], ds0); atomicAdd(&ed[rowbase + 0], dd0);
                atomicAdd(&es[rowbase + 1], ds1); atomicAdd(&ed[rowbase + 1], dd1);
                atomicAdd(&es[rowbase + 2], ds2); atomicAdd(&ed[rowbase + 2], dd2);
                atomicAdd(&es[rowbase + 3], ds3); atomicAdd(&ed[rowbase + 3], dd3);
            }
        }
    }
}

// ---------------- wave-per-dst SINGLE-PASS online-softmax aggregate (fp16 h) ----
// All 64 lanes of a wave see the identical edge stream for their dst, so the
// running (m, denom) is tracked redundantly per-lane: ZERO shuffles, ZERO wbuf
// traffic, one edge-list traversal instead of three. On a max update the
// 4-float per-lane accumulator is rescaled by exp(m_old - m_new) (flash-attn
// style). Final m equals the exact segment max -> same math as reference.
__global__ __launch_bounds__(256) void agg_kernel(const _Float16* __restrict__ h,
    const int* __restrict__ row_ptr, const int* __restrict__ src_sorted,
    const float* __restrict__ es, const float* __restrict__ ed,
    const float* __restrict__ bg, _Float16* __restrict__ g) {
    int gtid = blockIdx.x * 256 + threadIdx.x;
    int dst = gtid >> 6;
    int lane = threadIdx.x & 63;
    if (dst >= N_NODES) return;
    int start = row_ptr[dst];
    int end = row_ptr[dst + 1];
    float edd = ed[dst];
    const _Float16* hl = h + (size_t)lane * 4;   // this lane's 4-dim column slice

    float m = -1e30f;
    float denom = 0.f;
    float4 acc = make_float4(0.f, 0.f, 0.f, 0.f);

    int i = start;
    for (; i + 3 < end; i += 4) {
        int s0 = src_sorted[i + 0];
        int s1 = src_sorted[i + 1];
        int s2 = src_sorted[i + 2];
        int s3 = src_sorted[i + 3];
        // issue the 4 row loads + 4 es gathers up front (independent, overlap)
        f16x4 r0 = *(const f16x4*)(hl + (size_t)s0 * HIDDEN);
        f16x4 r1 = *(const f16x4*)(hl + (size_t)s1 * HIDDEN);
        f16x4 r2 = *(const f16x4*)(hl + (size_t)s2 * HIDDEN);
        f16x4 r3 = *(const f16x4*)(hl + (size_t)s3 * HIDDEN);
        float e0 = es[s0] + edd; e0 = (e0 > 0.f) ? e0 : NEG_SLOPE * e0;
        float e1 = es[s1] + edd; e1 = (e1 > 0.f) ? e1 : NEG_SLOPE * e1;
        float e2 = es[s2] + edd; e2 = (e2 > 0.f) ? e2 : NEG_SLOPE * e2;
        float e3 = es[s3] + edd; e3 = (e3 > 0.f) ? e3 : NEG_SLOPE * e3;
        float me = fmaxf(fmaxf(e0, e1), fmaxf(e2, e3));
        if (me > m) {                       // wave-uniform branch, rare
            float sc = __expf(m - me);      // exp(-inf)=0 on first hit: safe
            denom *= sc;
            acc.x *= sc; acc.y *= sc; acc.z *= sc; acc.w *= sc;
            m = me;
        }
        float w0 = __expf(e0 - m);
        float w1 = __expf(e1 - m);
        float w2 = __expf(e2 - m);
        float w3 = __expf(e3 - m);
        denom += (w0 + w1) + (w2 + w3);
        acc.x += w0 * (float)r0[0] + w1 * (float)r1[0] + w2 * (float)r2[0] + w3 * (float)r3[0];
        acc.y += w0 * (float)r0[1] + w1 * (float)r1[1] + w2 * (float)r2[1] + w3 * (float)r3[1];
        acc.z += w0 * (float)r0[2] + w1 * (float)r1[2] + w2 * (float)r2[2] + w3 * (float)r3[2];
        acc.w += w0 * (float)r0[3] + w1 * (float)r1[3] + w2 * (float)r2[3] + w3 * (float)r3[3];
    }
    for (; i < end; i++) {
        int s0 = src_sorted[i];
        f16x4 r0 = *(const f16x4*)(hl + (size_t)s0 * HIDDEN);
        float e0 = es[s0] + edd; e0 = (e0 > 0.f) ? e0 : NEG_SLOPE * e0;
        if (e0 > m) {
            float sc = __expf(m - e0);
            denom *= sc;
            acc.x *= sc; acc.y *= sc; acc.z *= sc; acc.w *= sc;
            m = e0;
        }
        float w0 = __expf(e0 - m);
        denom += w0;
        acc.x += w0 * (float)r0[0];
        acc.y += w0 * (float)r0[1];
        acc.z += w0 * (float)r0[2];
        acc.w += w0 * (float)r0[3];
    }

    float inv = 1.0f / (denom + SM_EPS);
    float4 b4 = *(const float4*)(bg + lane * 4);
    f16x4 outv;
    outv[0] = (_Float16)fmaxf(acc.x * inv + b4.x, 0.f);
    outv[1] = (_Float16)fmaxf(acc.y * inv + b4.y, 0.f);
    outv[2] = (_Float16)fmaxf(acc.z * inv + b4.z, 0.f);
    outv[3] = (_Float16)fmaxf(acc.w * inv + b4.w, 0.f);
    *(f16x4*)(g + (size_t)dst * HIDDEN + lane * 4) = outv;
}

// ---------------- graph boundaries: batch is SORTED -> binary search ----------------
__global__ __launch_bounds__(128) void graph_bounds_kernel(const int* __restrict__ batch,
    int* __restrict__ gstart) {
    int g = threadIdx.x;
    if (g > NUM_GRAPHS) return;
    if (g == NUM_GRAPHS) { gstart[NUM_GRAPHS] = N_NODES; return; }
    int lo = 0, hi = N_NODES;
    while (lo < hi) {
        int mid = (lo + hi) >> 1;
        if (batch[mid] < g) lo = mid + 1; else hi = mid;
    }
    gstart[g] = lo;
}

// ---------------- mean pool: owner-computes partial reduction (fp16 x) ----------------
#define POOL_SPLITS 16
__global__ __launch_bounds__(256) void pool_partial_kernel(const _Float16* __restrict__ x,
    const int* __restrict__ gstart, float* __restrict__ pooledT) {
    int g = blockIdx.x;
    int chunk = blockIdx.y;
    int t = threadIdx.x;
    int s = gstart[g];
    int e = gstart[g + 1];
    int n = e - s;
    int per = (n + POOL_SPLITS - 1) / POOL_SPLITS;
    int r0 = s + chunk * per;
    int r1 = min(r0 + per, e);
    if (r0 >= r1) return;
    float acc = 0.f;
    for (int r = r0; r < r1; r++) acc += (float)x[(size_t)r * HIDDEN + t];
    atomicAdd(&pooledT[t * NUM_GRAPHS + g], acc);
}

__global__ __launch_bounds__(256) void mean_kernel(const float* __restrict__ pooledT,
    const int* __restrict__ gstart, float* __restrict__ meanT) {
    int i = blockIdx.x * 256 + threadIdx.x;
    int g = i & (NUM_GRAPHS - 1);
    float c = (float)max(gstart[g + 1] - gstart[g], 1);
    meanT[i] = pooledT[i] / c;
}

// ---------------- final: out[64,50000] = pooled @ Wout + bout (fp32) ----------------
// Intra-block g-split: 256 threads = 64 j-columns x 4 g-chunks of 16.
// g0 is wave-uniform; readfirstlane PINS it to an SGPR so the compiler can
// prove the meanT address thread-uniform and scalarize those loads to
// s_load (round-2 lesson: without this, SGPR_Count=32 and each thread
// issued 4 vector loads/k -> 159us; with full uniformity it was s_load'd,
// SGPR_Count=96). Wout is streamed exactly once: all 4 waves read the same
// 64 floats per k (wave 0 misses, waves 1-3 hit L1). 782 blocks x 4 waves.
__global__ __launch_bounds__(256) void final_kernel(const float* __restrict__ meanT,
    const float* __restrict__ Wout, const float* __restrict__ bout, float* __restrict__ out) {
    int j = blockIdx.x * 64 + (threadIdx.x & 63);
    int g0 = __builtin_amdgcn_readfirstlane((threadIdx.x >> 6) * 16);  // SGPR, wave-uniform
    if (j >= VOCAB) return;
    float acc[16];
    #pragma unroll
    for (int g = 0; g < 16; g++) acc[g] = 0.f;
    #pragma unroll 4
    for (int k = 0; k < HIDDEN; k++) {
        float w = Wout[(size_t)k * VOCAB + j];
        const float* mrow = meanT + k * NUM_GRAPHS + g0;
        #pragma unroll
        for (int g = 0; g < 16; g++) acc[g] += mrow[g] * w;
    }
    float b = bout[j];
    #pragma unroll
    for (int g = 0; g < 16; g++) out[(size_t)(g0 + g) * VOCAB + j] = acc[g] + b;
}

extern "C" void kernel_launch(void* const* d_in, const int* in_sizes, int n_in,
                              void* d_out, int out_size, void* d_ws, size_t ws_size,
                              hipStream_t stream) {
    const int*   nodes = (const int*)d_in[0];
    const int*   ei    = (const int*)d_in[1];
    const int*   batch = (const int*)d_in[2];
    const float* emb   = (const float*)d_in[3];
    const float* Wg    = (const float*)d_in[4];
    const float* a_src = (const float*)d_in[5];
    const float* a_dst = (const float*)d_in[6];
    const float* bg    = (const float*)d_in[7];
    const float* Wl    = (const float*)d_in[8];
    const float* bl    = (const float*)d_in[9];
    const float* Wout  = (const float*)d_in[10];
    const float* bout  = (const float*)d_in[11];
    float* out = (float*)d_out;

    char* ws = (char*)d_ws;
    size_t off = 0;
    auto alloc = [&](size_t bytes) -> void* {
        void* p = ws + off;
        off += (bytes + 255) & ~(size_t)255;
        return p;
    };
    _Float16* bufA    = (_Float16*)alloc((size_t)N_NODES * HIDDEN * 2);
    _Float16* bufB    = (_Float16*)alloc((size_t)N_NODES * HIDDEN * 2);
    _Float16* WT      = (_Float16*)alloc((size_t)6 * HIDDEN * HIDDEN * 2);
    float* es         = (float*)alloc((size_t)N_NODES * 4);
    float* ed         = (float*)alloc((size_t)N_NODES * 4);
    int*   counts     = (int*)alloc((size_t)N_NODES * 4);
    int*   row_ptr    = (int*)alloc((size_t)(N_NODES + 1) * 4);
    int*   cursor     = (int*)alloc((size_t)N_NODES * 4);
    int*   src_sorted = (int*)alloc((size_t)E_TOTAL * 4);
    float* pooledT    = (float*)alloc((size_t)HIDDEN * NUM_GRAPHS * 4);
    float* meanT      = (float*)alloc((size_t)HIDDEN * NUM_GRAPHS * 4);
    int*   gstart     = (int*)alloc((size_t)(NUM_GRAPHS + 1) * 4);

    hipMemsetAsync(counts, 0, (size_t)N_NODES * 4, stream);
    hipMemsetAsync(pooledT, 0, (size_t)HIDDEN * NUM_GRAPHS * 4, stream);

    convert_wt_kernel<<<dim3(HIDDEN, 6), 256, 0, stream>>>(Wg, Wl, WT);
    gather_kernel<<<N_NODES, 256, 0, stream>>>(nodes, emb, bufA);
    hist_kernel<<<(E_TOTAL + 255) / 256, 256, 0, stream>>>(ei, counts);
    scan_kernel<<<1, 1024, 0, stream>>>(counts, row_ptr, cursor);
    scatter_kernel<<<(E_TOTAL + 255) / 256, 256, 0, stream>>>(ei, cursor, src_sorted);

    _Float16* cur = bufA;
    _Float16* oth = bufB;
    for (int l = 0; l < 3; l++) {
        // zero es/ed for the fused-partial atomics
        hipMemsetAsync(es, 0, (size_t)N_NODES * 4, stream);
        hipMemsetAsync(ed, 0, (size_t)N_NODES * 4, stream);
        gemm_f16_kernel<true><<<dim3(N_NODES / 128, 2), 256, 0, stream>>>(
            cur, WT + (size_t)l * HIDDEN * HIDDEN, nullptr, oth,
            a_src + (size_t)l * HIDDEN, a_dst + (size_t)l * HIDDEN, es, ed);
        agg_kernel<<<N_NODES / 4, 256, 0, stream>>>(
            oth, row_ptr, src_sorted, es, ed, bg + (size_t)l * HIDDEN, cur);
        gemm_f16_kernel<false><<<dim3(N_NODES / 128, 2), 256, 0, stream>>>(
            cur, WT + (size_t)(3 + l) * HIDDEN * HIDDEN, bl + (size_t)l * HIDDEN, oth,
            nullptr, nullptr, nullptr, nullptr);
        _Float16* t = cur; cur = oth; oth = t;
    }

    graph_bounds_kernel<<<1, 128, 0, stream>>>(batch, gstart);
    pool_partial_kernel<<<dim3(NUM_GRAPHS, POOL_SPLITS), 256, 0, stream>>>(cur, gstart, pooledT);
    mean_kernel<<<(HIDDEN * NUM_GRAPHS) / 256, 256, 0, stream>>>(pooledT, gstart, meanT);
    final_kernel<<<dim3((VOCAB + 63) / 64), 256, 0, stream>>>(meanT, Wout, bout, out);
}

// Round 4
// 826.700 us; speedup vs baseline: 1.1387x; 1.0106x over previous
//
#include <hip/hip_runtime.h>

#define N_NODES 65536
#define N_EDGES 1048576
#define E_TOTAL (N_EDGES + N_NODES)
#define VOCAB 50000
#define HIDDEN 256
#define NUM_GRAPHS 64
#define NEG_SLOPE 0.2f
#define SM_EPS 1e-16f

typedef _Float16 f16x8 __attribute__((ext_vector_type(8)));
typedef _Float16 f16x4 __attribute__((ext_vector_type(4)));
typedef float f32x4 __attribute__((ext_vector_type(4)));

// ---------------- gather: x = (fp16) emb[nodes] ----------------
__global__ __launch_bounds__(256) void gather_kernel(const int* __restrict__ nodes,
    const float* __restrict__ emb, _Float16* __restrict__ x) {
    int i = blockIdx.x;
    int t = threadIdx.x;
    x[(size_t)i * HIDDEN + t] = (_Float16)emb[(size_t)nodes[i] * HIDDEN + t];
}

// ---------------- weight transpose+convert: WT[mat][n][k] = (fp16) W[mat][k][n] ----------------
__global__ __launch_bounds__(256) void convert_wt_kernel(const float* __restrict__ Wg,
    const float* __restrict__ Wl, _Float16* __restrict__ WT) {
    int mat = blockIdx.y;
    int n = blockIdx.x;
    int k = threadIdx.x;
    const float* W = (mat < 3) ? (Wg + (size_t)mat * HIDDEN * HIDDEN)
                               : (Wl + (size_t)(mat - 3) * HIDDEN * HIDDEN);
    WT[(size_t)mat * HIDDEN * HIDDEN + (size_t)n * HIDDEN + k] = (_Float16)W[(size_t)k * HIDDEN + n];
}

// ---------------- CSR build (by dst) ----------------
__global__ __launch_bounds__(256) void hist_kernel(const int* __restrict__ ei, int* __restrict__ counts) {
    int e = blockIdx.x * 256 + threadIdx.x;
    if (e >= E_TOTAL) return;
    int dst = (e < N_EDGES) ? ei[N_EDGES + e] : (e - N_EDGES);
    atomicAdd(&counts[dst], 1);
}

__global__ __launch_bounds__(1024) void scan_kernel(const int* __restrict__ counts,
    int* __restrict__ row_ptr, int* __restrict__ cursor) {
    __shared__ int sp[1024];
    int t = threadIdx.x;
    int base = t * 64;
    int s = 0;
    for (int i = 0; i < 64; i++) s += counts[base + i];
    sp[t] = s;
    __syncthreads();
    for (int d = 1; d < 1024; d <<= 1) {
        int v = (t >= d) ? sp[t - d] : 0;
        __syncthreads();
        sp[t] += v;
        __syncthreads();
    }
    int run = sp[t] - s;
    for (int i = 0; i < 64; i++) {
        int c = counts[base + i];
        row_ptr[base + i] = run;
        cursor[base + i] = run;
        run += c;
    }
    if (t == 1023) row_ptr[N_NODES] = run;
}

__global__ __launch_bounds__(256) void scatter_kernel(const int* __restrict__ ei,
    int* __restrict__ cursor, int* __restrict__ src_sorted) {
    int e = blockIdx.x * 256 + threadIdx.x;
    if (e >= E_TOTAL) return;
    int src, dst;
    if (e < N_EDGES) { src = ei[e]; dst = ei[N_EDGES + e]; }
    else             { src = dst = e - N_EDGES; }
    int pos = atomicAdd(&cursor[dst], 1);
    src_sorted[pos] = src;
}

// ---------------- fp16 MFMA GEMM: BM=128, BN=128, BK=32, 1024 blocks (4/CU) ----
// C[M,256] = A[M,256] @ W (WT[n][k]). Grid (M/128, 2); blockIdx.y picks the
// 128-col half. FUSED: partial row-dots vs a_s/a_d atomicAdd'ed into es/ed
// (caller zeroes es/ed first). Template tag -> distinct mangled names in prof.
#define PAD_K 40
template <bool FUSED>
__global__ __launch_bounds__(256) void gemm_f16_kernel(const _Float16* __restrict__ A,
    const _Float16* __restrict__ WT, const float* __restrict__ bias,
    _Float16* __restrict__ C,
    const float* __restrict__ a_s, const float* __restrict__ a_d,
    float* __restrict__ es, float* __restrict__ ed) {
    __shared__ _Float16 As[128][PAD_K];   // 10240 B
    __shared__ _Float16 Bs[128][PAD_K];   // 10240 B
    int tid = threadIdx.x;
    int wave = tid >> 6;
    int lane = tid & 63;
    int quad = lane >> 4;
    int l16 = lane & 15;
    int m0 = blockIdx.x * 128;
    int n0 = blockIdx.y * 128;

    f32x4 acc[2][8];
    #pragma unroll
    for (int rt = 0; rt < 2; rt++)
        #pragma unroll
        for (int ct = 0; ct < 8; ct++)
            acc[rt][ct] = (f32x4){0.f, 0.f, 0.f, 0.f};

    for (int k0 = 0; k0 < HIDDEN; k0 += 32) {
        __syncthreads();
        // stage A: 128 rows x 32 halfs = 512 16B-chunks; 2 per thread
        #pragma unroll
        for (int i = 0; i < 2; i++) {
            int c = tid + i * 256;
            int row = c >> 2, q = c & 3;
            *(f16x8*)&As[row][q * 8] =
                *(const f16x8*)(A + (size_t)(m0 + row) * HIDDEN + k0 + q * 8);
        }
        // stage B: 128 rows (cols n0..n0+127) x 32 halfs; 2 per thread
        #pragma unroll
        for (int i = 0; i < 2; i++) {
            int c = tid + i * 256;
            int row = c >> 2, q = c & 3;
            *(f16x8*)&Bs[row][q * 8] =
                *(const f16x8*)(WT + (size_t)(n0 + row) * HIDDEN + k0 + q * 8);
        }
        __syncthreads();
        f16x8 a0 = *(const f16x8*)&As[wave * 32 + l16][quad * 8];
        f16x8 a1 = *(const f16x8*)&As[wave * 32 + 16 + l16][quad * 8];
        #pragma unroll
        for (int ct = 0; ct < 8; ct++) {
            f16x8 b = *(const f16x8*)&Bs[ct * 16 + l16][quad * 8];
            acc[0][ct] = __builtin_amdgcn_mfma_f32_16x16x32_f16(a0, b, acc[0][ct], 0, 0, 0);
            acc[1][ct] = __builtin_amdgcn_mfma_f32_16x16x32_f16(a1, b, acc[1][ct], 0, 0, 0);
        }
    }
    // epilogue: C/D layout col=lane&15, row=quad*4+reg
    #pragma unroll
    for (int rt = 0; rt < 2; rt++) {
        #pragma unroll
        for (int ct = 0; ct < 8; ct++) {
            int col = n0 + ct * 16 + l16;
            float bv = (bias != nullptr) ? bias[col] : 0.f;
            int rowbase = m0 + wave * 32 + rt * 16 + quad * 4;
            #pragma unroll
            for (int r = 0; r < 4; r++) {
                C[(size_t)(rowbase + r) * HIDDEN + col] = (_Float16)(acc[rt][ct][r] + bv);
            }
        }
    }
    // fused dots: partial over this block's 128 cols, atomicAdd into es/ed
    if (FUSED) {
        #pragma unroll
        for (int rt = 0; rt < 2; rt++) {
            float ds0 = 0.f, ds1 = 0.f, ds2 = 0.f, ds3 = 0.f;
            float dd0 = 0.f, dd1 = 0.f, dd2 = 0.f, dd3 = 0.f;
            #pragma unroll
            for (int ct = 0; ct < 8; ct++) {
                int col = n0 + ct * 16 + l16;
                float av = a_s[col];
                float dv = a_d[col];
                ds0 += acc[rt][ct][0] * av; dd0 += acc[rt][ct][0] * dv;
                ds1 += acc[rt][ct][1] * av; dd1 += acc[rt][ct][1] * dv;
                ds2 += acc[rt][ct][2] * av; dd2 += acc[rt][ct][2] * dv;
                ds3 += acc[rt][ct][3] * av; dd3 += acc[rt][ct][3] * dv;
            }
            #pragma unroll
            for (int off = 1; off < 16; off <<= 1) {
                ds0 += __shfl_xor(ds0, off); dd0 += __shfl_xor(dd0, off);
                ds1 += __shfl_xor(ds1, off); dd1 += __shfl_xor(dd1, off);
                ds2 += __shfl_xor(ds2, off); dd2 += __shfl_xor(dd2, off);
                ds3 += __shfl_xor(ds3, off); dd3 += __shfl_xor(dd3, off);
            }
            if (l16 == 0) {
                int rowbase = m0 + wave * 32 + rt * 16 + quad * 4;
                atomicAdd(&es[rowbase + 0], ds0); atomicAdd(&ed[rowbase + 0], dd0);
                atomicAdd(&es[rowbase + 1], ds1); atomicAdd(&ed[rowbase + 1], dd1);
                atomicAdd(&es[rowbase + 2], ds2); atomicAdd(&ed[rowbase + 2], dd2);
                atomicAdd(&es[rowbase + 3], ds3); atomicAdd(&ed[rowbase + 3], dd3);
            }
        }
    }
}

// ---------------- half-wave-per-dst SINGLE-PASS online-softmax aggregate ----
// 2 dsts per wave: lanes 0-31 own dst 2w, lanes 32-63 own dst 2w+1. Each lane
// covers 8 hidden dims (f16x8 = 16B loads, coalescing sweet spot). The
// per-edge scalar stream (es gather, leaky, online max, exp, denom, addr
// calc) is replicated per HALF instead of per wave -> ~2x less redundant
// VALU work per edge, and two independent edge streams per wave double the
// MLP against L2/L3 gather latency. Per-dst math is the identical sequence
// to the 1-wave version (same 4-unroll, same online max) -> bitwise same.
__global__ __launch_bounds__(256) void agg_kernel(const _Float16* __restrict__ h,
    const int* __restrict__ row_ptr, const int* __restrict__ src_sorted,
    const float* __restrict__ es, const float* __restrict__ ed,
    const float* __restrict__ bg, _Float16* __restrict__ g) {
    int dst = blockIdx.x * 8 + (threadIdx.x >> 5);   // 8 dsts per 256-thread block
    int l32 = threadIdx.x & 31;
    int start = row_ptr[dst];
    int end = row_ptr[dst + 1];
    float edd = ed[dst];
    const _Float16* hl = h + l32 * 8;   // this lane's 8-dim column slice

    float m = -1e30f;
    float denom = 0.f;
    float acc[8];
    #pragma unroll
    for (int j = 0; j < 8; j++) acc[j] = 0.f;

    int i = start;
    for (; i + 3 < end; i += 4) {
        int s0 = src_sorted[i + 0];
        int s1 = src_sorted[i + 1];
        int s2 = src_sorted[i + 2];
        int s3 = src_sorted[i + 3];
        // 4 independent 16B row-slice loads + 4 es gathers in flight
        f16x8 r0 = *(const f16x8*)(hl + (unsigned)s0 * HIDDEN);
        f16x8 r1 = *(const f16x8*)(hl + (unsigned)s1 * HIDDEN);
        f16x8 r2 = *(const f16x8*)(hl + (unsigned)s2 * HIDDEN);
        f16x8 r3 = *(const f16x8*)(hl + (unsigned)s3 * HIDDEN);
        float e0 = es[s0] + edd; e0 = (e0 > 0.f) ? e0 : NEG_SLOPE * e0;
        float e1 = es[s1] + edd; e1 = (e1 > 0.f) ? e1 : NEG_SLOPE * e1;
        float e2 = es[s2] + edd; e2 = (e2 > 0.f) ? e2 : NEG_SLOPE * e2;
        float e3 = es[s3] + edd; e3 = (e3 > 0.f) ? e3 : NEG_SLOPE * e3;
        float me = fmaxf(fmaxf(e0, e1), fmaxf(e2, e3));
        if (me > m) {                       // half-uniform, predicated; rare
            float sc = __expf(m - me);      // exp(-inf)=0 on first hit: safe
            denom *= sc;
            #pragma unroll
            for (int j = 0; j < 8; j++) acc[j] *= sc;
            m = me;
        }
        float w0 = __expf(e0 - m);
        float w1 = __expf(e1 - m);
        float w2 = __expf(e2 - m);
        float w3 = __expf(e3 - m);
        denom += (w0 + w1) + (w2 + w3);
        #pragma unroll
        for (int j = 0; j < 8; j++)
            acc[j] += w0 * (float)r0[j] + w1 * (float)r1[j]
                    + w2 * (float)r2[j] + w3 * (float)r3[j];
    }
    for (; i < end; i++) {
        int s0 = src_sorted[i];
        f16x8 r0 = *(const f16x8*)(hl + (unsigned)s0 * HIDDEN);
        float e0 = es[s0] + edd; e0 = (e0 > 0.f) ? e0 : NEG_SLOPE * e0;
        if (e0 > m) {
            float sc = __expf(m - e0);
            denom *= sc;
            #pragma unroll
            for (int j = 0; j < 8; j++) acc[j] *= sc;
            m = e0;
        }
        float w0 = __expf(e0 - m);
        denom += w0;
        #pragma unroll
        for (int j = 0; j < 8; j++) acc[j] += w0 * (float)r0[j];
    }

    float inv = 1.0f / (denom + SM_EPS);
    float4 b0 = *(const float4*)(bg + l32 * 8);
    float4 b1 = *(const float4*)(bg + l32 * 8 + 4);
    f16x8 outv;
    outv[0] = (_Float16)fmaxf(acc[0] * inv + b0.x, 0.f);
    outv[1] = (_Float16)fmaxf(acc[1] * inv + b0.y, 0.f);
    outv[2] = (_Float16)fmaxf(acc[2] * inv + b0.z, 0.f);
    outv[3] = (_Float16)fmaxf(acc[3] * inv + b0.w, 0.f);
    outv[4] = (_Float16)fmaxf(acc[4] * inv + b1.x, 0.f);
    outv[5] = (_Float16)fmaxf(acc[5] * inv + b1.y, 0.f);
    outv[6] = (_Float16)fmaxf(acc[6] * inv + b1.z, 0.f);
    outv[7] = (_Float16)fmaxf(acc[7] * inv + b1.w, 0.f);
    *(f16x8*)(g + (size_t)dst * HIDDEN + l32 * 8) = outv;
}

// ---------------- graph boundaries: batch is SORTED -> binary search ----------------
__global__ __launch_bounds__(128) void graph_bounds_kernel(const int* __restrict__ batch,
    int* __restrict__ gstart) {
    int g = threadIdx.x;
    if (g > NUM_GRAPHS) return;
    if (g == NUM_GRAPHS) { gstart[NUM_GRAPHS] = N_NODES; return; }
    int lo = 0, hi = N_NODES;
    while (lo < hi) {
        int mid = (lo + hi) >> 1;
        if (batch[mid] < g) lo = mid + 1; else hi = mid;
    }
    gstart[g] = lo;
}

// ---------------- mean pool: owner-computes partial reduction (fp16 x) ----------------
#define POOL_SPLITS 16
__global__ __launch_bounds__(256) void pool_partial_kernel(const _Float16* __restrict__ x,
    const int* __restrict__ gstart, float* __restrict__ pooledT) {
    int g = blockIdx.x;
    int chunk = blockIdx.y;
    int t = threadIdx.x;
    int s = gstart[g];
    int e = gstart[g + 1];
    int n = e - s;
    int per = (n + POOL_SPLITS - 1) / POOL_SPLITS;
    int r0 = s + chunk * per;
    int r1 = min(r0 + per, e);
    if (r0 >= r1) return;
    float acc = 0.f;
    for (int r = r0; r < r1; r++) acc += (float)x[(size_t)r * HIDDEN + t];
    atomicAdd(&pooledT[t * NUM_GRAPHS + g], acc);
}

__global__ __launch_bounds__(256) void mean_kernel(const float* __restrict__ pooledT,
    const int* __restrict__ gstart, float* __restrict__ meanT) {
    int i = blockIdx.x * 256 + threadIdx.x;
    int g = i & (NUM_GRAPHS - 1);
    float c = (float)max(gstart[g + 1] - gstart[g], 1);
    meanT[i] = pooledT[i] / c;
}

// ---------------- final: out[64,50000] = pooled @ Wout + bout (fp32) ----------------
// Intra-block g-split: 256 threads = 64 j-columns x 4 g-chunks of 16.
// g0 is wave-uniform; readfirstlane PINS it to an SGPR so the compiler can
// prove the meanT address thread-uniform and scalarize those loads to
// s_load (round-2 lesson: without this, SGPR_Count=32 and each thread
// issued 4 vector loads/k -> 159us; with full uniformity it was s_load'd,
// SGPR_Count=96). Wout is streamed exactly once: all 4 waves read the same
// 64 floats per k (wave 0 misses, waves 1-3 hit L1). 782 blocks x 4 waves.
__global__ __launch_bounds__(256) void final_kernel(const float* __restrict__ meanT,
    const float* __restrict__ Wout, const float* __restrict__ bout, float* __restrict__ out) {
    int j = blockIdx.x * 64 + (threadIdx.x & 63);
    int g0 = __builtin_amdgcn_readfirstlane((threadIdx.x >> 6) * 16);  // SGPR, wave-uniform
    if (j >= VOCAB) return;
    float acc[16];
    #pragma unroll
    for (int g = 0; g < 16; g++) acc[g] = 0.f;
    #pragma unroll 4
    for (int k = 0; k < HIDDEN; k++) {
        float w = Wout[(size_t)k * VOCAB + j];
        const float* mrow = meanT + k * NUM_GRAPHS + g0;
        #pragma unroll
        for (int g = 0; g < 16; g++) acc[g] += mrow[g] * w;
    }
    float b = bout[j];
    #pragma unroll
    for (int g = 0; g < 16; g++) out[(size_t)(g0 + g) * VOCAB + j] = acc[g] + b;
}

extern "C" void kernel_launch(void* const* d_in, const int* in_sizes, int n_in,
                              void* d_out, int out_size, void* d_ws, size_t ws_size,
                              hipStream_t stream) {
    const int*   nodes = (const int*)d_in[0];
    const int*   ei    = (const int*)d_in[1];
    const int*   batch = (const int*)d_in[2];
    const float* emb   = (const float*)d_in[3];
    const float* Wg    = (const float*)d_in[4];
    const float* a_src = (const float*)d_in[5];
    const float* a_dst = (const float*)d_in[6];
    const float* bg    = (const float*)d_in[7];
    const float* Wl    = (const float*)d_in[8];
    const float* bl    = (const float*)d_in[9];
    const float* Wout  = (const float*)d_in[10];
    const float* bout  = (const float*)d_in[11];
    float* out = (float*)d_out;

    char* ws = (char*)d_ws;
    size_t off = 0;
    auto alloc = [&](size_t bytes) -> void* {
        void* p = ws + off;
        off += (bytes + 255) & ~(size_t)255;
        return p;
    };
    _Float16* bufA    = (_Float16*)alloc((size_t)N_NODES * HIDDEN * 2);
    _Float16* bufB    = (_Float16*)alloc((size_t)N_NODES * HIDDEN * 2);
    _Float16* WT      = (_Float16*)alloc((size_t)6 * HIDDEN * HIDDEN * 2);
    float* es         = (float*)alloc((size_t)N_NODES * 4);
    float* ed         = (float*)alloc((size_t)N_NODES * 4);
    int*   counts     = (int*)alloc((size_t)N_NODES * 4);
    int*   row_ptr    = (int*)alloc((size_t)(N_NODES + 1) * 4);
    int*   cursor     = (int*)alloc((size_t)N_NODES * 4);
    int*   src_sorted = (int*)alloc((size_t)E_TOTAL * 4);
    float* pooledT    = (float*)alloc((size_t)HIDDEN * NUM_GRAPHS * 4);
    float* meanT      = (float*)alloc((size_t)HIDDEN * NUM_GRAPHS * 4);
    int*   gstart     = (int*)alloc((size_t)(NUM_GRAPHS + 1) * 4);

    hipMemsetAsync(counts, 0, (size_t)N_NODES * 4, stream);
    hipMemsetAsync(pooledT, 0, (size_t)HIDDEN * NUM_GRAPHS * 4, stream);

    convert_wt_kernel<<<dim3(HIDDEN, 6), 256, 0, stream>>>(Wg, Wl, WT);
    gather_kernel<<<N_NODES, 256, 0, stream>>>(nodes, emb, bufA);
    hist_kernel<<<(E_TOTAL + 255) / 256, 256, 0, stream>>>(ei, counts);
    scan_kernel<<<1, 1024, 0, stream>>>(counts, row_ptr, cursor);
    scatter_kernel<<<(E_TOTAL + 255) / 256, 256, 0, stream>>>(ei, cursor, src_sorted);

    _Float16* cur = bufA;
    _Float16* oth = bufB;
    for (int l = 0; l < 3; l++) {
        // zero es/ed for the fused-partial atomics
        hipMemsetAsync(es, 0, (size_t)N_NODES * 4, stream);
        hipMemsetAsync(ed, 0, (size_t)N_NODES * 4, stream);
        gemm_f16_kernel<true><<<dim3(N_NODES / 128, 2), 256, 0, stream>>>(
            cur, WT + (size_t)l * HIDDEN * HIDDEN, nullptr, oth,
            a_src + (size_t)l * HIDDEN, a_dst + (size_t)l * HIDDEN, es, ed);
        agg_kernel<<<N_NODES / 8, 256, 0, stream>>>(
            oth, row_ptr, src_sorted, es, ed, bg + (size_t)l * HIDDEN, cur);
        gemm_f16_kernel<false><<<dim3(N_NODES / 128, 2), 256, 0, stream>>>(
            cur, WT + (size_t)(3 + l) * HIDDEN * HIDDEN, bl + (size_t)l * HIDDEN, oth,
            nullptr, nullptr, nullptr, nullptr);
        _Float16* t = cur; cur = oth; oth = t;
    }

    graph_bounds_kernel<<<1, 128, 0, stream>>>(batch, gstart);
    pool_partial_kernel<<<dim3(NUM_GRAPHS, POOL_SPLITS), 256, 0, stream>>>(cur, gstart, pooledT);
    mean_kernel<<<(HIDDEN * NUM_GRAPHS) / 256, 256, 0, stream>>>(pooledT, gstart, meanT);
    final_kernel<<<dim3((VOCAB + 63) / 64), 256, 0, stream>>>(meanT, Wout, bout, out);
}